// Round 8
// baseline (183.620 us; speedup 1.0000x reference)
//
#include <hip/hip_runtime.h>

#define N_NODES 50000
#define N_EDGES 800000
#define D 128
#define NB 782            // ceil(50000/64) buckets of 64 nodes
#define SLICE_ELEMS 800000  // 50000 rows x 16 cols per slice (u16 elems)

typedef __attribute__((ext_vector_type(8))) short bf16x8;   // MFMA A/B frag
typedef __attribute__((ext_vector_type(4))) float floatx4;  // MFMA C/D frag

__device__ __forceinline__ unsigned short f2bf(float f) {
  unsigned u = __builtin_bit_cast(unsigned, f);
  unsigned r = u + 0x7FFFu + ((u >> 16) & 1u);  // RNE
  return (unsigned short)(r >> 16);
}
__device__ __forceinline__ float bf2f_lo(unsigned u) {
  return __builtin_bit_cast(float, u << 16);
}
__device__ __forceinline__ float bf2f_hi(unsigned u) {
  return __builtin_bit_cast(float, u & 0xFFFF0000u);
}

// ===========================================================================
// bin_agg: block-aggregated bucket binning.
// R7 lesson: 800K value-returning global atomics on 782 cursors = ~1023-deep
// serialized RMW chains (~47us).  Here: LDS histogram -> block scan -> ONE
// atomic per (block,bucket) (depth 250) -> LDS-staged scatter -> flush in
// bucket-grouped runs (~4 entries) for dense line writes.
// ===========================================================================
#define BIN_T 512
#define BIN_CHUNK 3200
#define BIN_BLOCKS 250   // 250*3200 = 800000 exactly

__global__ __launch_bounds__(BIN_T) void bin_agg(
    const int* __restrict__ src, const int* __restrict__ dst,
    int* __restrict__ bcursor, unsigned* __restrict__ ebuf, int cap) {
  __shared__ unsigned stage[BIN_CHUNK];          // 12.8 KB
  __shared__ unsigned short stageb[BIN_CHUNK];   // 6.4 KB
  __shared__ int hcnt[NB];
  __shared__ int hstart[NB];
  __shared__ int hcur[NB];
  __shared__ int hgbase[NB];
  __shared__ int wsums[8];

  int t = threadIdx.x;
  int e0 = blockIdx.x * BIN_CHUNK;
  for (int i = t; i < NB; i += BIN_T) hcnt[i] = 0;
  __syncthreads();

  unsigned pk[7];
  short bk[7];
#pragma unroll
  for (int j = 0; j < 7; ++j) {
    int idx = j * BIN_T + t;
    bk[j] = -1;
    if (idx < BIN_CHUNK) {
      int e = e0 + idx;           // always < N_EDGES (250*3200 exact)
      int d = dst[e];
      int s = src[e];
      pk[j] = ((unsigned)s << 6) | (unsigned)(d & 63);
      bk[j] = (short)(d >> 6);
      atomicAdd(&hcnt[d >> 6], 1);
    }
  }
  __syncthreads();

  // exclusive scan of hcnt[782]: 2 counters per thread, block scan.
  int i0 = 2 * t, i1 = 2 * t + 1;
  int c0 = (i0 < NB) ? hcnt[i0] : 0;
  int c1 = (i1 < NB) ? hcnt[i1] : 0;
  int s2 = c0 + c1;
  int incl = s2;
  int lane = t & 63, wid = t >> 6;
#pragma unroll
  for (int off = 1; off < 64; off <<= 1) {
    int n = __shfl_up(incl, off);
    if (lane >= off) incl += n;
  }
  if (lane == 63) wsums[wid] = incl;
  __syncthreads();
  int wbase = 0;
  for (int w2 = 0; w2 < wid; ++w2) wbase += wsums[w2];
  int base = wbase + incl - s2;
  if (i0 < NB) { hstart[i0] = base;      hcur[i0] = base; }
  if (i1 < NB) { hstart[i1] = base + c0; hcur[i1] = base + c0; }
  __syncthreads();

  // reserve global space: one atomic per nonempty bucket
  for (int i = t; i < NB; i += BIN_T) {
    int c = hcnt[i];
    hgbase[i] = c ? atomicAdd(&bcursor[i * 16], c) : 0;
  }
  // scatter into stage grouped by bucket (scalar LDS atomics only)
#pragma unroll
  for (int j = 0; j < 7; ++j) {
    if (bk[j] >= 0) {
      int p = atomicAdd(&hcur[bk[j]], 1);
      stage[p] = pk[j];
      stageb[p] = (unsigned short)bk[j];
    }
  }
  __syncthreads();

  // flush: consecutive stage slots of one bucket -> consecutive global addrs
  for (int i = t; i < BIN_CHUNK; i += BIN_T) {
    int b = stageb[i];
    int g = hgbase[b] + (i - hstart[b]);
    if (g < cap) ebuf[(size_t)b * cap + g] = stage[i];
  }
}

// ===========================================================================
// sort_bucket: one block per bucket.  Counting sort by dst-local (scalar LDS
// atomics), then overwrite own ebuf region with sorted u16 src list; starts
// (65 ints) to starts_g.  Safe alias: all entries read to registers first.
// ===========================================================================
__global__ __launch_bounds__(256) void sort_bucket(
    const int* __restrict__ bcursor, unsigned* __restrict__ ebuf,
    int* __restrict__ starts_g, int cap) {
  __shared__ int cnts[64];
  __shared__ int curs[64];
  __shared__ int starts[65];
  int b = blockIdx.x, t = threadIdx.x;
  if (t < 64) cnts[t] = 0;
  __syncthreads();
  int cnt = bcursor[b * 16];
  if (cnt > cap) cnt = cap;
  unsigned* eb = ebuf + (size_t)b * cap;

  unsigned mine[8];
  int m = 0;
  for (int i = t; i < cnt; i += 256) {
    unsigned u = eb[i];
    mine[m++] = u;
    atomicAdd(&cnts[u & 63u], 1);
  }
  __syncthreads();
  if (t < 64) {
    int c = cnts[t];
    int v = c;
#pragma unroll
    for (int off = 1; off < 64; off <<= 1) {
      int n = __shfl_up(v, off);
      if (t >= off) v += n;
    }
    starts[t] = v - c;
    curs[t] = v - c;
    if (t == 63) starts[64] = v;
  }
  __syncthreads();
  unsigned short* es = (unsigned short*)eb;  // alias own region (all read)
  m = 0;
  for (int i = t; i < cnt; i += 256) {
    unsigned u = mine[m++];
    int p = atomicAdd(&curs[u & 63u], 1);
    es[p] = (unsigned short)(u >> 6);
  }
  if (t < 65) starts_g[b * 72 + t] = starts[t];
}

// ===========================================================================
// GEMM: y = bf16( x @ W^T ).  Tile 128x128, K=128.  slice=1 writes y in
// slice-major layout y[s][node][16cols] (8 slices of 1.6 MB) for L2-resident
// per-XCD gather; slice=0 writes row-major (CSR fallback path).
// ===========================================================================
#define LDA 136
__global__ __launch_bounds__(256) void gemm_xw(
    const float* __restrict__ x, const float* __restrict__ W,
    unsigned short* __restrict__ y, int slice) {
  __shared__ unsigned short As[128 * LDA];
  __shared__ unsigned short Ws[128 * LDA];

  int t = threadIdx.x;
  int row0 = blockIdx.x * 128;

  for (int i = t; i < 4096; i += 256) {
    int r = i >> 5;
    int c4 = (i & 31) * 4;
    int gr = row0 + r;
    float4 v = (gr < N_NODES) ? *(const float4*)(x + (size_t)gr * D + c4)
                              : float4{0.f, 0.f, 0.f, 0.f};
    unsigned short* p = &As[r * LDA + c4];
    p[0] = f2bf(v.x); p[1] = f2bf(v.y); p[2] = f2bf(v.z); p[3] = f2bf(v.w);
    float4 wv = *(const float4*)(W + (size_t)r * D + c4);
    unsigned short* q = &Ws[r * LDA + c4];
    q[0] = f2bf(wv.x); q[1] = f2bf(wv.y); q[2] = f2bf(wv.z); q[3] = f2bf(wv.w);
  }
  __syncthreads();

  int w = t >> 6;
  int lane = t & 63;
  int ln = lane & 15;
  int quad = lane >> 4;

  floatx4 acc[2][8];
#pragma unroll
  for (int m = 0; m < 2; ++m)
#pragma unroll
    for (int n = 0; n < 8; ++n) acc[m][n] = floatx4{0.f, 0.f, 0.f, 0.f};

#pragma unroll
  for (int ks = 0; ks < 4; ++ks) {
    int kc = ks * 32 + quad * 8;
    bf16x8 a0 = *(const bf16x8*)&As[(w * 32 + ln) * LDA + kc];
    bf16x8 a1 = *(const bf16x8*)&As[(w * 32 + 16 + ln) * LDA + kc];
#pragma unroll
    for (int n = 0; n < 8; ++n) {
      bf16x8 bf = *(const bf16x8*)&Ws[(n * 16 + ln) * LDA + kc];
      acc[0][n] = __builtin_amdgcn_mfma_f32_16x16x32_bf16(a0, bf, acc[0][n], 0, 0, 0);
      acc[1][n] = __builtin_amdgcn_mfma_f32_16x16x32_bf16(a1, bf, acc[1][n], 0, 0, 0);
    }
  }

  // D layout: col = lane&15, row = quad*4 + reg.  For slice mode, slice id
  // == n (ln < 16), col-in-slice == ln.
#pragma unroll
  for (int m = 0; m < 2; ++m) {
    int gr0 = row0 + w * 32 + m * 16 + quad * 4;
#pragma unroll
    for (int n = 0; n < 8; ++n) {
#pragma unroll
      for (int r = 0; r < 4; ++r) {
        int gr = gr0 + r;
        if (gr < N_NODES) {
          if (slice)
            y[(size_t)n * SLICE_ELEMS + (size_t)gr * 16 + ln] = f2bf(acc[m][n][r]);
          else
            y[(size_t)gr * D + n * 16 + ln] = f2bf(acc[m][n][r]);
        }
      }
    }
  }
}

// ===========================================================================
// gather_slice: block (bucket b, slice c= blockIdx%8).  With %8 ~ XCD
// round-robin, each XCD touches only its 1.6 MB y-slice -> L2-resident.
// Lane layout: slot=lane>>3 (8 edges in flight), part=lane&7 (dword = 2
// cols).  shfl_xor(8/16/32) reduce, fused bias, float2 store (64B/node).
// ===========================================================================
__global__ __launch_bounds__(256) void gather_slice(
    const unsigned short* __restrict__ ysl, const unsigned* __restrict__ ebuf,
    const int* __restrict__ starts_g, const float* __restrict__ bias,
    float* __restrict__ out, int cap) {
  __shared__ int starts[65];
  int c = blockIdx.x & 7;
  int b = blockIdx.x >> 3;
  int t = threadIdx.x;
  if (t < 65) starts[t] = starts_g[b * 72 + t];
  __syncthreads();

  const unsigned short* es = (const unsigned short*)(ebuf + (size_t)b * cap);
  const unsigned short* yp = ysl + (size_t)c * SLICE_ELEMS;
  int wv = t >> 6, lane = t & 63;
  int slot = lane >> 3, part = lane & 7;
  float bvx = bias[c * 16 + part * 2];
  float bvy = bias[c * 16 + part * 2 + 1];

  for (int n = wv; n < 64; n += 4) {
    int beg = starts[n], end = starts[n + 1];
    float a0 = 0.f, a1 = 0.f, a2 = 0.f, a3 = 0.f;
    int i = beg + slot;
    for (; i + 8 < end; i += 16) {
      int s0 = es[i];
      int s1 = es[i + 8];
      unsigned v0 = *(const unsigned*)(yp + (size_t)s0 * 16 + part * 2);
      unsigned v1 = *(const unsigned*)(yp + (size_t)s1 * 16 + part * 2);
      a0 += bf2f_lo(v0); a1 += bf2f_hi(v0);
      a2 += bf2f_lo(v1); a3 += bf2f_hi(v1);
    }
    if (i < end) {
      int s = es[i];
      unsigned v = *(const unsigned*)(yp + (size_t)s * 16 + part * 2);
      a0 += bf2f_lo(v); a1 += bf2f_hi(v);
    }
    a0 += a2; a1 += a3;
#pragma unroll
    for (int off = 8; off < 64; off <<= 1) {
      a0 += __shfl_xor(a0, off);
      a1 += __shfl_xor(a1, off);
    }
    int node = b * 64 + n;
    if (lane < 8 && node < N_NODES)
      *(float2*)(out + (size_t)node * D + c * 16 + part * 2) =
          float2{a0 + bvx, a1 + bvy};
  }
}

// ===========================================================================
// Fallback tier 1: R5 CSR path
// ===========================================================================
__global__ __launch_bounds__(256) void hist_kernel(
    const int* __restrict__ dst, int* __restrict__ counts) {
  int e = blockIdx.x * 256 + threadIdx.x;
  if (e < N_EDGES) atomicAdd(&counts[dst[e]], 1);
}

#define SBLK 196
__global__ __launch_bounds__(256) void reduce_kernel(
    const int* __restrict__ counts, int* __restrict__ blockSums) {
  int i = blockIdx.x * 256 + threadIdx.x;
  int v = (i < N_NODES) ? counts[i] : 0;
#pragma unroll
  for (int off = 32; off; off >>= 1) v += __shfl_down(v, off);
  __shared__ int ws[4];
  int lane = threadIdx.x & 63, wid = threadIdx.x >> 6;
  if (lane == 0) ws[wid] = v;
  __syncthreads();
  if (threadIdx.x == 0) blockSums[blockIdx.x] = ws[0] + ws[1] + ws[2] + ws[3];
}

__global__ __launch_bounds__(256) void scan_kernel2(
    const int* __restrict__ counts, const int* __restrict__ blockSums,
    int* __restrict__ offsets, int* __restrict__ cursor) {
  int b = blockIdx.x;
  int t = threadIdx.x;
  int lane = t & 63, wid = t >> 6;
  int pv = (t < b) ? blockSums[t] : 0;
#pragma unroll
  for (int off = 32; off; off >>= 1) pv += __shfl_down(pv, off);
  __shared__ int ws[4];
  __shared__ int wsum[4];
  __shared__ int base_s;
  if (lane == 0) ws[wid] = pv;
  __syncthreads();
  if (t == 0) base_s = ws[0] + ws[1] + ws[2] + ws[3];
  int i = b * 256 + t;
  int c = (i < N_NODES) ? counts[i] : 0;
  int v = c;
#pragma unroll
  for (int off = 1; off < 64; off <<= 1) {
    int n = __shfl_up(v, off);
    if (lane >= off) v += n;
  }
  if (lane == 63) wsum[wid] = v;
  __syncthreads();
  int wbase = 0;
  for (int w2 = 0; w2 < wid; ++w2) wbase += wsum[w2];
  int excl = base_s + wbase + v - c;
  if (i < N_NODES) {
    offsets[i] = excl;
    cursor[i] = excl;
    if (i == N_NODES - 1) offsets[N_NODES] = excl + c;
  }
}

__global__ __launch_bounds__(256) void fill_kernel(
    const int* __restrict__ src, const int* __restrict__ dst,
    int* __restrict__ cursor, int* __restrict__ esrc) {
  int e = blockIdx.x * 256 + threadIdx.x;
  if (e >= N_EDGES) return;
  int pos = atomicAdd(&cursor[dst[e]], 1);
  esrc[pos] = src[e];
}

__global__ __launch_bounds__(256) void gather_ybf_kernel(
    const unsigned short* __restrict__ y, const int* __restrict__ esrc,
    const int* __restrict__ offsets, const float* __restrict__ bias,
    float* __restrict__ out) {
  int node = blockIdx.x * 4 + (threadIdx.x >> 6);
  if (node >= N_NODES) return;
  int lane = threadIdx.x & 63;
  int g = lane >> 4;
  int l = lane & 15;
  int beg = offsets[node];
  int end = offsets[node + 1];
  float acc[8] = {0.f, 0.f, 0.f, 0.f, 0.f, 0.f, 0.f, 0.f};
  int i = beg + g;
  for (; i + 4 < end; i += 8) {
    int s0 = esrc[i];
    int s1 = esrc[i + 4];
    uint4 u0 = *(const uint4*)(y + (size_t)s0 * D + l * 8);
    uint4 u1 = *(const uint4*)(y + (size_t)s1 * D + l * 8);
    acc[0] += bf2f_lo(u0.x) + bf2f_lo(u1.x);
    acc[1] += bf2f_hi(u0.x) + bf2f_hi(u1.x);
    acc[2] += bf2f_lo(u0.y) + bf2f_lo(u1.y);
    acc[3] += bf2f_hi(u0.y) + bf2f_hi(u1.y);
    acc[4] += bf2f_lo(u0.z) + bf2f_lo(u1.z);
    acc[5] += bf2f_hi(u0.z) + bf2f_hi(u1.z);
    acc[6] += bf2f_lo(u0.w) + bf2f_lo(u1.w);
    acc[7] += bf2f_hi(u0.w) + bf2f_hi(u1.w);
  }
  if (i < end) {
    int s = esrc[i];
    uint4 u = *(const uint4*)(y + (size_t)s * D + l * 8);
    acc[0] += bf2f_lo(u.x); acc[1] += bf2f_hi(u.x);
    acc[2] += bf2f_lo(u.y); acc[3] += bf2f_hi(u.y);
    acc[4] += bf2f_lo(u.z); acc[5] += bf2f_hi(u.z);
    acc[6] += bf2f_lo(u.w); acc[7] += bf2f_hi(u.w);
  }
#pragma unroll
  for (int j = 0; j < 8; ++j) {
    acc[j] += __shfl_xor(acc[j], 16);
    acc[j] += __shfl_xor(acc[j], 32);
  }
  if (g == 0) {
    const float* bp = bias + l * 8;
    float4 r0 = {acc[0] + bp[0], acc[1] + bp[1], acc[2] + bp[2], acc[3] + bp[3]};
    float4 r1 = {acc[4] + bp[4], acc[5] + bp[5], acc[6] + bp[6], acc[7] + bp[7]};
    float* op = out + (size_t)node * D + l * 8;
    *(float4*)op = r0;
    *(float4*)(op + 4) = r1;
  }
}

// ===========================================================================
// Fallback tier 2: atomic scatter + f32 transform.
// ===========================================================================
__global__ __launch_bounds__(256) void scatter_kernel(
    const float* __restrict__ x, const int* __restrict__ src,
    const int* __restrict__ dst, float* __restrict__ out) {
  int gtid = blockIdx.x * 256 + threadIdx.x;
  int e = gtid >> 6;
  int lane = threadIdx.x & 63;
  if (e >= N_EDGES) return;
  float2 v = ((const float2*)(x + (size_t)src[e] * D))[lane];
  float* orow = out + (size_t)dst[e] * D + lane * 2;
  atomicAdd(orow + 0, v.x);
  atomicAdd(orow + 1, v.y);
}

__global__ __launch_bounds__(256) void transform_kernel(
    float* __restrict__ out, const float* __restrict__ W,
    const float* __restrict__ bias) {
  constexpr int RPB = 64;
  constexpr int HP = 132;
  __shared__ float Hs[RPB][HP];
  int t = threadIdx.x;
  int row0 = blockIdx.x * RPB;
  int nr = min(RPB, N_NODES - row0);
  {
    const float4* g = (const float4*)(out + (size_t)row0 * D);
    for (int i = t; i < nr * (D / 4); i += 256) {
      int r = i >> 5;
      int c = (i & 31) * 4;
      *(float4*)&Hs[r][c] = g[i];
    }
  }
  __syncthreads();
  int tx = t & 15;
  int ty = t >> 4;
  int r0 = ty * 4;
  for (int half = 0; half < 2; ++half) {
    int oc0 = half * 64 + tx * 4;
    const float* Wb = W + (size_t)oc0 * D;
    float4 a0 = {0.f, 0.f, 0.f, 0.f}, a1 = {0.f, 0.f, 0.f, 0.f};
    float4 a2 = {0.f, 0.f, 0.f, 0.f}, a3 = {0.f, 0.f, 0.f, 0.f};
#pragma unroll 8
    for (int k = 0; k < D; k += 4) {
      float4 w0 = *(const float4*)(Wb + 0 * D + k);
      float4 w1 = *(const float4*)(Wb + 1 * D + k);
      float4 w2 = *(const float4*)(Wb + 2 * D + k);
      float4 w3 = *(const float4*)(Wb + 3 * D + k);
      float4 h0 = *(const float4*)&Hs[r0 + 0][k];
      float4 h1 = *(const float4*)&Hs[r0 + 1][k];
      float4 h2 = *(const float4*)&Hs[r0 + 2][k];
      float4 h3 = *(const float4*)&Hs[r0 + 3][k];
#define DOT(hv, wv) fmaf((hv).w, (wv).w, fmaf((hv).z, (wv).z, fmaf((hv).y, (wv).y, (hv).x * (wv).x)))
      a0.x += DOT(h0, w0); a0.y += DOT(h0, w1); a0.z += DOT(h0, w2); a0.w += DOT(h0, w3);
      a1.x += DOT(h1, w0); a1.y += DOT(h1, w1); a1.z += DOT(h1, w2); a1.w += DOT(h1, w3);
      a2.x += DOT(h2, w0); a2.y += DOT(h2, w1); a2.z += DOT(h2, w2); a2.w += DOT(h2, w3);
      a3.x += DOT(h3, w0); a3.y += DOT(h3, w1); a3.z += DOT(h3, w2); a3.w += DOT(h3, w3);
#undef DOT
    }
    float4 bv = *(const float4*)(bias + oc0);
    a0.x += bv.x; a0.y += bv.y; a0.z += bv.z; a0.w += bv.w;
    a1.x += bv.x; a1.y += bv.y; a1.z += bv.z; a1.w += bv.w;
    a2.x += bv.x; a2.y += bv.y; a2.z += bv.z; a2.w += bv.w;
    a3.x += bv.x; a3.y += bv.y; a3.z += bv.z; a3.w += bv.w;
    if (r0 + 0 < nr) *(float4*)(out + (size_t)(row0 + r0 + 0) * D + oc0) = a0;
    if (r0 + 1 < nr) *(float4*)(out + (size_t)(row0 + r0 + 1) * D + oc0) = a1;
    if (r0 + 2 < nr) *(float4*)(out + (size_t)(row0 + r0 + 2) * D + oc0) = a2;
    if (r0 + 3 < nr) *(float4*)(out + (size_t)(row0 + r0 + 3) * D + oc0) = a3;
  }
}

extern "C" void kernel_launch(void* const* d_in, const int* in_sizes, int n_in,
                              void* d_out, int out_size, void* d_ws, size_t ws_size,
                              hipStream_t stream) {
  const float* x = (const float*)d_in[0];
  const int* src = (const int*)d_in[1];
  const int* dst = (const int*)d_in[2];
  const float* W = (const float*)d_in[3];
  const float* b = (const float*)d_in[4];
  float* out = (float*)d_out;

  const size_t ybytes = 8 * (size_t)SLICE_ELEMS * sizeof(unsigned short);  // 12.8 MB
  const size_t bcbytes = (size_t)NB * 16 * sizeof(int);                    // 50 KB
  const size_t stbytes = (size_t)NB * 72 * sizeof(int);                    // 225 KB

  // Dynamic bucket capacity; bucket sizes ~Poisson(1024), sigma 32.
  long long avail = (long long)ws_size - (long long)ybytes -
                    (long long)bcbytes - (long long)stbytes;
  int cap = 0;
  if (avail > 0) {
    long long c = avail / (4LL * NB);
    cap = (c > 2048) ? 2048 : (int)c;
  }

  if (cap >= 1344) {  // mean + 10 sigma
    unsigned short* y = (unsigned short*)d_ws;
    int* bcursor = (int*)((char*)d_ws + ybytes);
    int* starts_g = (int*)((char*)bcursor + bcbytes);
    unsigned* ebuf = (unsigned*)((char*)starts_g + stbytes);

    hipMemsetAsync(bcursor, 0, bcbytes, stream);
    bin_agg<<<BIN_BLOCKS, BIN_T, 0, stream>>>(src, dst, bcursor, ebuf, cap);
    sort_bucket<<<NB, 256, 0, stream>>>(bcursor, ebuf, starts_g, cap);
    gemm_xw<<<(N_NODES + 127) / 128, 256, 0, stream>>>(x, W, y, 1);
    gather_slice<<<NB * 8, 256, 0, stream>>>(y, ebuf, starts_g, b, out, cap);
    return;
  }

  const size_t A = 50048;
  const size_t head_ints = 3 * A + 256 + (size_t)N_EDGES;
  const size_t need_csr = head_ints * sizeof(int) +
                          (size_t)N_NODES * D * sizeof(unsigned short);

  if (ws_size >= need_csr) {
    int* counts     = (int*)d_ws;
    int* offsets    = counts + A;
    int* cursor     = offsets + A;
    int* blockSums  = cursor + A;
    int* esrc       = blockSums + 256;
    unsigned short* y = (unsigned short*)(esrc + N_EDGES);

    hipMemsetAsync(counts, 0, N_NODES * sizeof(int), stream);
    hist_kernel<<<(N_EDGES + 255) / 256, 256, 0, stream>>>(dst, counts);
    reduce_kernel<<<SBLK, 256, 0, stream>>>(counts, blockSums);
    scan_kernel2<<<SBLK, 256, 0, stream>>>(counts, blockSums, offsets, cursor);
    fill_kernel<<<(N_EDGES + 255) / 256, 256, 0, stream>>>(src, dst, cursor, esrc);
    gemm_xw<<<(N_NODES + 127) / 128, 256, 0, stream>>>(x, W, y, 0);
    gather_ybf_kernel<<<(N_NODES + 3) / 4, 256, 0, stream>>>(y, esrc, offsets, b, out);
  } else {
    hipMemsetAsync(out, 0, (size_t)N_NODES * D * sizeof(float), stream);
    scatter_kernel<<<N_EDGES / 4, 256, 0, stream>>>(x, src, dst, out);
    transform_kernel<<<(N_NODES + 63) / 64, 256, 0, stream>>>(out, W, b);
  }
}

// Round 9
// 152.783 us; speedup vs baseline: 1.2018x; 1.2018x over previous
//
#include <hip/hip_runtime.h>

#define N_NODES 50000
#define N_EDGES 800000
#define D 128
#define NB 782            // ceil(50000/64) buckets of 64 nodes
#define SORT_CAP 2048

typedef __attribute__((ext_vector_type(8))) short bf16x8;   // MFMA A/B frag
typedef __attribute__((ext_vector_type(4))) float floatx4;  // MFMA C/D frag

__device__ __forceinline__ unsigned short f2bf(float f) {
  unsigned u = __builtin_bit_cast(unsigned, f);
  unsigned r = u + 0x7FFFu + ((u >> 16) & 1u);  // RNE
  return (unsigned short)(r >> 16);
}
__device__ __forceinline__ float bf2f_lo(unsigned u) {
  return __builtin_bit_cast(float, u << 16);
}
__device__ __forceinline__ float bf2f_hi(unsigned u) {
  return __builtin_bit_cast(float, u & 0xFFFF0000u);
}

// ===========================================================================
// bin_agg: block-aggregated bucket binning (R8, proven).
// LDS histogram -> block scan -> ONE global atomic per (block,bucket)
// (chain depth 250, not 1023) -> LDS-staged scatter -> dense run flush.
// ===========================================================================
#define BIN_T 512
#define BIN_CHUNK 3200
#define BIN_BLOCKS 250   // 250*3200 = 800000 exactly

__global__ __launch_bounds__(BIN_T) void bin_agg(
    const int* __restrict__ src, const int* __restrict__ dst,
    int* __restrict__ bcursor, unsigned* __restrict__ ebuf, int cap) {
  __shared__ unsigned stage[BIN_CHUNK];          // 12.8 KB
  __shared__ unsigned short stageb[BIN_CHUNK];   // 6.4 KB
  __shared__ int hcnt[NB];
  __shared__ int hstart[NB];
  __shared__ int hcur[NB];
  __shared__ int hgbase[NB];
  __shared__ int wsums[8];

  int t = threadIdx.x;
  int e0 = blockIdx.x * BIN_CHUNK;
  for (int i = t; i < NB; i += BIN_T) hcnt[i] = 0;
  __syncthreads();

  unsigned pk[7];
  short bk[7];
#pragma unroll
  for (int j = 0; j < 7; ++j) {
    int idx = j * BIN_T + t;
    bk[j] = -1;
    if (idx < BIN_CHUNK) {
      int e = e0 + idx;
      int d = dst[e];
      int s = src[e];
      pk[j] = ((unsigned)s << 6) | (unsigned)(d & 63);
      bk[j] = (short)(d >> 6);
      atomicAdd(&hcnt[d >> 6], 1);
    }
  }
  __syncthreads();

  // exclusive scan of hcnt[782]: 2 counters/thread, block scan
  int i0 = 2 * t, i1 = 2 * t + 1;
  int c0 = (i0 < NB) ? hcnt[i0] : 0;
  int c1 = (i1 < NB) ? hcnt[i1] : 0;
  int s2 = c0 + c1;
  int incl = s2;
  int lane = t & 63, wid = t >> 6;
#pragma unroll
  for (int off = 1; off < 64; off <<= 1) {
    int n = __shfl_up(incl, off);
    if (lane >= off) incl += n;
  }
  if (lane == 63) wsums[wid] = incl;
  __syncthreads();
  int wbase = 0;
  for (int w2 = 0; w2 < wid; ++w2) wbase += wsums[w2];
  int base = wbase + incl - s2;
  if (i0 < NB) { hstart[i0] = base;      hcur[i0] = base; }
  if (i1 < NB) { hstart[i1] = base + c0; hcur[i1] = base + c0; }
  __syncthreads();

  for (int i = t; i < NB; i += BIN_T) {
    int c = hcnt[i];
    hgbase[i] = c ? atomicAdd(&bcursor[i * 16], c) : 0;
  }
#pragma unroll
  for (int j = 0; j < 7; ++j) {
    if (bk[j] >= 0) {
      int p = atomicAdd(&hcur[bk[j]], 1);
      stage[p] = pk[j];
      stageb[p] = (unsigned short)bk[j];
    }
  }
  __syncthreads();

  for (int i = t; i < BIN_CHUNK; i += BIN_T) {
    int b = stageb[i];
    int g = hgbase[b] + (i - hstart[b]);
    if (g < cap) ebuf[(size_t)b * cap + g] = stage[i];
  }
}

// ===========================================================================
// GEMM: y[50000,128] = bf16( x @ W^T ), row-major y.
// 64-row tiles -> 782 blocks = 3.05 blocks/CU (128-row tiles gave 391
// blocks = 1.53/CU: half the CUs ran two sequential block-waves).
// LDS 52 KB -> 3 blocks/CU.
// ===========================================================================
#define LDA 136
__global__ __launch_bounds__(256) void gemm_xw(
    const float* __restrict__ x, const float* __restrict__ W,
    unsigned short* __restrict__ y) {
  __shared__ unsigned short As[64 * LDA];    // 17.4 KB
  __shared__ unsigned short Ws[128 * LDA];   // 34.8 KB

  int t = threadIdx.x;
  int row0 = blockIdx.x * 64;

  // stage x tile (64 rows) and all of W (128 rows), f32 -> bf16
  for (int i = t; i < 2048; i += 256) {
    int r = i >> 5;
    int c4 = (i & 31) * 4;
    int gr = row0 + r;
    float4 v = (gr < N_NODES) ? *(const float4*)(x + (size_t)gr * D + c4)
                              : float4{0.f, 0.f, 0.f, 0.f};
    unsigned short* p = &As[r * LDA + c4];
    p[0] = f2bf(v.x); p[1] = f2bf(v.y); p[2] = f2bf(v.z); p[3] = f2bf(v.w);
  }
  for (int i = t; i < 4096; i += 256) {
    int r = i >> 5;
    int c4 = (i & 31) * 4;
    float4 wv = *(const float4*)(W + (size_t)r * D + c4);
    unsigned short* q = &Ws[r * LDA + c4];
    q[0] = f2bf(wv.x); q[1] = f2bf(wv.y); q[2] = f2bf(wv.z); q[3] = f2bf(wv.w);
  }
  __syncthreads();

  int w = t >> 6;          // wave w: rows [w*16, w*16+16)
  int lane = t & 63;
  int ln = lane & 15;
  int quad = lane >> 4;

  floatx4 acc[8];
#pragma unroll
  for (int n = 0; n < 8; ++n) acc[n] = floatx4{0.f, 0.f, 0.f, 0.f};

#pragma unroll
  for (int ks = 0; ks < 4; ++ks) {
    int kc = ks * 32 + quad * 8;
    bf16x8 a = *(const bf16x8*)&As[(w * 16 + ln) * LDA + kc];
#pragma unroll
    for (int n = 0; n < 8; ++n) {
      bf16x8 bf = *(const bf16x8*)&Ws[(n * 16 + ln) * LDA + kc];
      acc[n] = __builtin_amdgcn_mfma_f32_16x16x32_bf16(a, bf, acc[n], 0, 0, 0);
    }
  }

  // D layout: col = lane&15, row = quad*4 + reg.
  int gr0 = row0 + w * 16 + quad * 4;
#pragma unroll
  for (int n = 0; n < 8; ++n) {
    int gc = n * 16 + ln;
#pragma unroll
    for (int r = 0; r < 4; ++r) {
      int gr = gr0 + r;
      if (gr < N_NODES) y[(size_t)gr * D + gc] = f2bf(acc[n][r]);
    }
  }
}

// ===========================================================================
// gather_sorted (R7, proven): block per bucket.  In-LDS counting sort by
// local dst (scalar int LDS atomics only), then wave-per-node register
// gather.  v2: 4-deep unroll (4 outstanding dwordx4/wave; one wave-iter
// covers a mean node segment).  y row-major: 16-lane group reads a full
// 256 B row per uint4 -> max bytes per instruction (R8's slice variant was
// VALU-bound on 8x redundant per-edge work).
// ===========================================================================
__global__ __launch_bounds__(256) void gather_sorted(
    const unsigned short* __restrict__ y, const unsigned* __restrict__ ebuf,
    const int* __restrict__ bcursor, const float* __restrict__ bias,
    float* __restrict__ out, int cap) {
  __shared__ int cnts[64];
  __shared__ int curs[64];
  __shared__ int starts[65];
  __shared__ int sorted[SORT_CAP];

  int b = blockIdx.x;
  int t = threadIdx.x;
  if (t < 64) cnts[t] = 0;
  __syncthreads();

  int cnt = bcursor[b * 16];
  if (cnt > cap) cnt = cap;
  if (cnt > SORT_CAP) cnt = SORT_CAP;
  const unsigned* eb = ebuf + (size_t)b * cap;

  // 1) count
  for (int i = t; i < cnt; i += 256) atomicAdd(&cnts[eb[i] & 63u], 1);
  __syncthreads();

  // 2) exclusive scan of 64 counters (wave 0)
  if (t < 64) {
    int c = cnts[t];
    int v = c;
#pragma unroll
    for (int off = 1; off < 64; off <<= 1) {
      int n = __shfl_up(v, off);
      if (t >= off) v += n;
    }
    starts[t] = v - c;
    curs[t] = v - c;
    if (t == 63) starts[64] = v;
  }
  __syncthreads();

  // 3) scatter src ids into sorted order
  for (int i = t; i < cnt; i += 256) {
    unsigned u = eb[i];
    int p = atomicAdd(&curs[u & 63u], 1);
    sorted[p] = (int)(u >> 6);
  }
  __syncthreads();

  // 4) wave-per-node gather, 4 edges in flight per 16-lane group
  int wv = t >> 6;
  int lane = t & 63;
  int g = lane >> 4;   // edge subgroup 0..3
  int l = lane & 15;   // 8-col chunk within row
  for (int n = wv; n < 64; n += 4) {
    int node = b * 64 + n;
    int beg = starts[n];
    int end = starts[n + 1];
    float acc[8] = {0.f, 0.f, 0.f, 0.f, 0.f, 0.f, 0.f, 0.f};
    int i = beg + g;
    for (; i + 12 < end; i += 16) {
      int s0 = sorted[i];
      int s1 = sorted[i + 4];
      int s2 = sorted[i + 8];
      int s3 = sorted[i + 12];
      uint4 u0 = *(const uint4*)(y + (size_t)s0 * D + l * 8);
      uint4 u1 = *(const uint4*)(y + (size_t)s1 * D + l * 8);
      uint4 u2 = *(const uint4*)(y + (size_t)s2 * D + l * 8);
      uint4 u3 = *(const uint4*)(y + (size_t)s3 * D + l * 8);
      acc[0] += (bf2f_lo(u0.x) + bf2f_lo(u1.x)) + (bf2f_lo(u2.x) + bf2f_lo(u3.x));
      acc[1] += (bf2f_hi(u0.x) + bf2f_hi(u1.x)) + (bf2f_hi(u2.x) + bf2f_hi(u3.x));
      acc[2] += (bf2f_lo(u0.y) + bf2f_lo(u1.y)) + (bf2f_lo(u2.y) + bf2f_lo(u3.y));
      acc[3] += (bf2f_hi(u0.y) + bf2f_hi(u1.y)) + (bf2f_hi(u2.y) + bf2f_hi(u3.y));
      acc[4] += (bf2f_lo(u0.z) + bf2f_lo(u1.z)) + (bf2f_lo(u2.z) + bf2f_lo(u3.z));
      acc[5] += (bf2f_hi(u0.z) + bf2f_hi(u1.z)) + (bf2f_hi(u2.z) + bf2f_hi(u3.z));
      acc[6] += (bf2f_lo(u0.w) + bf2f_lo(u1.w)) + (bf2f_lo(u2.w) + bf2f_lo(u3.w));
      acc[7] += (bf2f_hi(u0.w) + bf2f_hi(u1.w)) + (bf2f_hi(u2.w) + bf2f_hi(u3.w));
    }
    for (; i < end; i += 4) {
      int s = sorted[i];
      uint4 u = *(const uint4*)(y + (size_t)s * D + l * 8);
      acc[0] += bf2f_lo(u.x); acc[1] += bf2f_hi(u.x);
      acc[2] += bf2f_lo(u.y); acc[3] += bf2f_hi(u.y);
      acc[4] += bf2f_lo(u.z); acc[5] += bf2f_hi(u.z);
      acc[6] += bf2f_lo(u.w); acc[7] += bf2f_hi(u.w);
    }
#pragma unroll
    for (int j = 0; j < 8; ++j) {
      acc[j] += __shfl_xor(acc[j], 16);
      acc[j] += __shfl_xor(acc[j], 32);
    }
    if (g == 0 && node < N_NODES) {
      const float* bp = bias + l * 8;
      float4 r0 = {acc[0] + bp[0], acc[1] + bp[1], acc[2] + bp[2], acc[3] + bp[3]};
      float4 r1 = {acc[4] + bp[4], acc[5] + bp[5], acc[6] + bp[6], acc[7] + bp[7]};
      float* op = out + (size_t)node * D + l * 8;
      *(float4*)op = r0;
      *(float4*)(op + 4) = r1;
    }
  }
}

// ===========================================================================
// Fallback tier 1: CSR path (R5)
// ===========================================================================
__global__ __launch_bounds__(256) void hist_kernel(
    const int* __restrict__ dst, int* __restrict__ counts) {
  int e = blockIdx.x * 256 + threadIdx.x;
  if (e < N_EDGES) atomicAdd(&counts[dst[e]], 1);
}

#define SBLK 196
__global__ __launch_bounds__(256) void reduce_kernel(
    const int* __restrict__ counts, int* __restrict__ blockSums) {
  int i = blockIdx.x * 256 + threadIdx.x;
  int v = (i < N_NODES) ? counts[i] : 0;
#pragma unroll
  for (int off = 32; off; off >>= 1) v += __shfl_down(v, off);
  __shared__ int ws[4];
  int lane = threadIdx.x & 63, wid = threadIdx.x >> 6;
  if (lane == 0) ws[wid] = v;
  __syncthreads();
  if (threadIdx.x == 0) blockSums[blockIdx.x] = ws[0] + ws[1] + ws[2] + ws[3];
}

__global__ __launch_bounds__(256) void scan_kernel2(
    const int* __restrict__ counts, const int* __restrict__ blockSums,
    int* __restrict__ offsets, int* __restrict__ cursor) {
  int b = blockIdx.x;
  int t = threadIdx.x;
  int lane = t & 63, wid = t >> 6;
  int pv = (t < b) ? blockSums[t] : 0;
#pragma unroll
  for (int off = 32; off; off >>= 1) pv += __shfl_down(pv, off);
  __shared__ int ws[4];
  __shared__ int wsum[4];
  __shared__ int base_s;
  if (lane == 0) ws[wid] = pv;
  __syncthreads();
  if (t == 0) base_s = ws[0] + ws[1] + ws[2] + ws[3];
  int i = b * 256 + t;
  int c = (i < N_NODES) ? counts[i] : 0;
  int v = c;
#pragma unroll
  for (int off = 1; off < 64; off <<= 1) {
    int n = __shfl_up(v, off);
    if (lane >= off) v += n;
  }
  if (lane == 63) wsum[wid] = v;
  __syncthreads();
  int wbase = 0;
  for (int w2 = 0; w2 < wid; ++w2) wbase += wsum[w2];
  int excl = base_s + wbase + v - c;
  if (i < N_NODES) {
    offsets[i] = excl;
    cursor[i] = excl;
    if (i == N_NODES - 1) offsets[N_NODES] = excl + c;
  }
}

__global__ __launch_bounds__(256) void fill_kernel(
    const int* __restrict__ src, const int* __restrict__ dst,
    int* __restrict__ cursor, int* __restrict__ esrc) {
  int e = blockIdx.x * 256 + threadIdx.x;
  if (e >= N_EDGES) return;
  int pos = atomicAdd(&cursor[dst[e]], 1);
  esrc[pos] = src[e];
}

__global__ __launch_bounds__(256) void gather_ybf_kernel(
    const unsigned short* __restrict__ y, const int* __restrict__ esrc,
    const int* __restrict__ offsets, const float* __restrict__ bias,
    float* __restrict__ out) {
  int node = blockIdx.x * 4 + (threadIdx.x >> 6);
  if (node >= N_NODES) return;
  int lane = threadIdx.x & 63;
  int g = lane >> 4;
  int l = lane & 15;
  int beg = offsets[node];
  int end = offsets[node + 1];
  float acc[8] = {0.f, 0.f, 0.f, 0.f, 0.f, 0.f, 0.f, 0.f};
  int i = beg + g;
  for (; i + 4 < end; i += 8) {
    int s0 = esrc[i];
    int s1 = esrc[i + 4];
    uint4 u0 = *(const uint4*)(y + (size_t)s0 * D + l * 8);
    uint4 u1 = *(const uint4*)(y + (size_t)s1 * D + l * 8);
    acc[0] += bf2f_lo(u0.x) + bf2f_lo(u1.x);
    acc[1] += bf2f_hi(u0.x) + bf2f_hi(u1.x);
    acc[2] += bf2f_lo(u0.y) + bf2f_lo(u1.y);
    acc[3] += bf2f_hi(u0.y) + bf2f_hi(u1.y);
    acc[4] += bf2f_lo(u0.z) + bf2f_lo(u1.z);
    acc[5] += bf2f_hi(u0.z) + bf2f_hi(u1.z);
    acc[6] += bf2f_lo(u0.w) + bf2f_lo(u1.w);
    acc[7] += bf2f_hi(u0.w) + bf2f_hi(u1.w);
  }
  if (i < end) {
    int s = esrc[i];
    uint4 u = *(const uint4*)(y + (size_t)s * D + l * 8);
    acc[0] += bf2f_lo(u.x); acc[1] += bf2f_hi(u.x);
    acc[2] += bf2f_lo(u.y); acc[3] += bf2f_hi(u.y);
    acc[4] += bf2f_lo(u.z); acc[5] += bf2f_hi(u.z);
    acc[6] += bf2f_lo(u.w); acc[7] += bf2f_hi(u.w);
  }
#pragma unroll
  for (int j = 0; j < 8; ++j) {
    acc[j] += __shfl_xor(acc[j], 16);
    acc[j] += __shfl_xor(acc[j], 32);
  }
  if (g == 0) {
    const float* bp = bias + l * 8;
    float4 r0 = {acc[0] + bp[0], acc[1] + bp[1], acc[2] + bp[2], acc[3] + bp[3]};
    float4 r1 = {acc[4] + bp[4], acc[5] + bp[5], acc[6] + bp[6], acc[7] + bp[7]};
    float* op = out + (size_t)node * D + l * 8;
    *(float4*)op = r0;
    *(float4*)(op + 4) = r1;
  }
}

// ===========================================================================
// Fallback tier 2: atomic scatter + f32 transform.
// ===========================================================================
__global__ __launch_bounds__(256) void scatter_kernel(
    const float* __restrict__ x, const int* __restrict__ src,
    const int* __restrict__ dst, float* __restrict__ out) {
  int gtid = blockIdx.x * 256 + threadIdx.x;
  int e = gtid >> 6;
  int lane = threadIdx.x & 63;
  if (e >= N_EDGES) return;
  float2 v = ((const float2*)(x + (size_t)src[e] * D))[lane];
  float* orow = out + (size_t)dst[e] * D + lane * 2;
  atomicAdd(orow + 0, v.x);
  atomicAdd(orow + 1, v.y);
}

__global__ __launch_bounds__(256) void transform_kernel(
    float* __restrict__ out, const float* __restrict__ W,
    const float* __restrict__ bias) {
  constexpr int RPB = 64;
  constexpr int HP = 132;
  __shared__ float Hs[RPB][HP];
  int t = threadIdx.x;
  int row0 = blockIdx.x * RPB;
  int nr = min(RPB, N_NODES - row0);
  {
    const float4* g = (const float4*)(out + (size_t)row0 * D);
    for (int i = t; i < nr * (D / 4); i += 256) {
      int r = i >> 5;
      int c = (i & 31) * 4;
      *(float4*)&Hs[r][c] = g[i];
    }
  }
  __syncthreads();
  int tx = t & 15;
  int ty = t >> 4;
  int r0 = ty * 4;
  for (int half = 0; half < 2; ++half) {
    int oc0 = half * 64 + tx * 4;
    const float* Wb = W + (size_t)oc0 * D;
    float4 a0 = {0.f, 0.f, 0.f, 0.f}, a1 = {0.f, 0.f, 0.f, 0.f};
    float4 a2 = {0.f, 0.f, 0.f, 0.f}, a3 = {0.f, 0.f, 0.f, 0.f};
#pragma unroll 8
    for (int k = 0; k < D; k += 4) {
      float4 w0 = *(const float4*)(Wb + 0 * D + k);
      float4 w1 = *(const float4*)(Wb + 1 * D + k);
      float4 w2 = *(const float4*)(Wb + 2 * D + k);
      float4 w3 = *(const float4*)(Wb + 3 * D + k);
      float4 h0 = *(const float4*)&Hs[r0 + 0][k];
      float4 h1 = *(const float4*)&Hs[r0 + 1][k];
      float4 h2 = *(const float4*)&Hs[r0 + 2][k];
      float4 h3 = *(const float4*)&Hs[r0 + 3][k];
#define DOT(hv, wv) fmaf((hv).w, (wv).w, fmaf((hv).z, (wv).z, fmaf((hv).y, (wv).y, (hv).x * (wv).x)))
      a0.x += DOT(h0, w0); a0.y += DOT(h0, w1); a0.z += DOT(h0, w2); a0.w += DOT(h0, w3);
      a1.x += DOT(h1, w0); a1.y += DOT(h1, w1); a1.z += DOT(h1, w2); a1.w += DOT(h1, w3);
      a2.x += DOT(h2, w0); a2.y += DOT(h2, w1); a2.z += DOT(h2, w2); a2.w += DOT(h2, w3);
      a3.x += DOT(h3, w0); a3.y += DOT(h3, w1); a3.z += DOT(h3, w2); a3.w += DOT(h3, w3);
#undef DOT
    }
    float4 bv = *(const float4*)(bias + oc0);
    a0.x += bv.x; a0.y += bv.y; a0.z += bv.z; a0.w += bv.w;
    a1.x += bv.x; a1.y += bv.y; a1.z += bv.z; a1.w += bv.w;
    a2.x += bv.x; a2.y += bv.y; a2.z += bv.z; a2.w += bv.w;
    a3.x += bv.x; a3.y += bv.y; a3.z += bv.z; a3.w += bv.w;
    if (r0 + 0 < nr) *(float4*)(out + (size_t)(row0 + r0 + 0) * D + oc0) = a0;
    if (r0 + 1 < nr) *(float4*)(out + (size_t)(row0 + r0 + 1) * D + oc0) = a1;
    if (r0 + 2 < nr) *(float4*)(out + (size_t)(row0 + r0 + 2) * D + oc0) = a2;
    if (r0 + 3 < nr) *(float4*)(out + (size_t)(row0 + r0 + 3) * D + oc0) = a3;
  }
}

extern "C" void kernel_launch(void* const* d_in, const int* in_sizes, int n_in,
                              void* d_out, int out_size, void* d_ws, size_t ws_size,
                              hipStream_t stream) {
  const float* x = (const float*)d_in[0];
  const int* src = (const int*)d_in[1];
  const int* dst = (const int*)d_in[2];
  const float* W = (const float*)d_in[3];
  const float* b = (const float*)d_in[4];
  float* out = (float*)d_out;

  const size_t ybytes = (size_t)N_NODES * D * sizeof(unsigned short);  // 12.8 MB
  const size_t bcbytes = (size_t)NB * 16 * sizeof(int);                // 50 KB

  long long avail = (long long)ws_size - (long long)ybytes - (long long)bcbytes;
  int cap = 0;
  if (avail > 0) {
    long long c = avail / (4LL * NB);
    cap = (c > SORT_CAP) ? SORT_CAP : (int)c;
  }

  if (cap >= 1344) {  // bucket sizes ~Poisson(1024): mean + 10 sigma
    unsigned short* y = (unsigned short*)d_ws;
    int* bcursor = (int*)((char*)d_ws + ybytes);
    unsigned* ebuf = (unsigned*)((char*)bcursor + bcbytes);

    hipMemsetAsync(bcursor, 0, bcbytes, stream);
    bin_agg<<<BIN_BLOCKS, BIN_T, 0, stream>>>(src, dst, bcursor, ebuf, cap);
    gemm_xw<<<NB, 256, 0, stream>>>(x, W, y);
    gather_sorted<<<NB, 256, 0, stream>>>(y, ebuf, bcursor, b, out, cap);
    return;
  }

  const size_t A = 50048;
  const size_t head_ints = 3 * A + 256 + (size_t)N_EDGES;
  const size_t need_csr = head_ints * sizeof(int) + ybytes;

  if (ws_size >= need_csr) {
    int* counts     = (int*)d_ws;
    int* offsets    = counts + A;
    int* cursor     = offsets + A;
    int* blockSums  = cursor + A;
    int* esrc       = blockSums + 256;
    unsigned short* y = (unsigned short*)(esrc + N_EDGES);

    hipMemsetAsync(counts, 0, N_NODES * sizeof(int), stream);
    hist_kernel<<<(N_EDGES + 255) / 256, 256, 0, stream>>>(dst, counts);
    reduce_kernel<<<SBLK, 256, 0, stream>>>(counts, blockSums);
    scan_kernel2<<<SBLK, 256, 0, stream>>>(counts, blockSums, offsets, cursor);
    fill_kernel<<<(N_EDGES + 255) / 256, 256, 0, stream>>>(src, dst, cursor, esrc);
    gemm_xw<<<NB, 256, 0, stream>>>(x, W, y);
    gather_ybf_kernel<<<(N_NODES + 3) / 4, 256, 0, stream>>>(y, esrc, offsets, b, out);
  } else {
    hipMemsetAsync(out, 0, (size_t)N_NODES * D * sizeof(float), stream);
    scatter_kernel<<<N_EDGES / 4, 256, 0, stream>>>(x, src, dst, out);
    transform_kernel<<<(N_NODES + 63) / 64, 256, 0, stream>>>(out, W, b);
  }
}

// Round 11
// 150.391 us; speedup vs baseline: 1.2210x; 1.0159x over previous
//
#include <hip/hip_runtime.h>

#define N_NODES 50000
#define N_EDGES 800000
#define D 128
#define NB 782            // ceil(50000/64) buckets of 64 nodes
#define SORT_CAP 2048

typedef __attribute__((ext_vector_type(8))) short bf16x8;   // MFMA A/B frag
typedef __attribute__((ext_vector_type(4))) float floatx4;  // MFMA C/D frag

__device__ __forceinline__ unsigned short f2bf(float f) {
  unsigned u = __builtin_bit_cast(unsigned, f);
  unsigned r = u + 0x7FFFu + ((u >> 16) & 1u);  // RNE
  return (unsigned short)(r >> 16);
}
__device__ __forceinline__ float bf2f_lo(unsigned u) {
  return __builtin_bit_cast(float, u << 16);
}
__device__ __forceinline__ float bf2f_hi(unsigned u) {
  return __builtin_bit_cast(float, u & 0xFFFF0000u);
}

// ===========================================================================
// prep_kernel: fused [gemm tiles | bin blocks] in one grid.
// bin (atomic/VALU-bound) and gemm (MFMA-bound) have no dependency; m114:
// MFMA-only and VALU-only waves co-schedule at ~max, not sum.  Gemm tiles
// first (longer per block -> LPT).  LDS is a union (52.2 KB -> 3 blocks/CU).
// ===========================================================================
#define LDA 136
#define BIN_T 256
#define BIN_CHUNK 2048
#define BIN_BLOCKS 391   // 391*2048 = 800768 >= 800000 (last block partial)

struct BinShm {
  unsigned stage[BIN_CHUNK];         // 8 KB
  unsigned short stageb[BIN_CHUNK];  // 4 KB
  int hcnt[NB];
  int hstart[NB];
  int hcur[NB];
  int hgbase[NB];
  int wsums[4];
  int tot;
};
struct GemmShm {
  unsigned short As[64 * LDA];    // 17.4 KB
  unsigned short Ws[128 * LDA];   // 34.8 KB
};
union PrepShm {
  BinShm bin;
  GemmShm gemm;
};

__global__ __launch_bounds__(256) void prep_kernel(
    const float* __restrict__ x, const float* __restrict__ W,
    unsigned short* __restrict__ y,
    const int* __restrict__ src, const int* __restrict__ dst,
    int* __restrict__ bcursor, unsigned* __restrict__ ebuf, int cap) {
  __shared__ PrepShm shm;
  int t = threadIdx.x;

  if (blockIdx.x < NB) {
    // ---------------- GEMM tile: y[row0..row0+64) = bf16(x @ W^T) ----------
    unsigned short* As = shm.gemm.As;
    unsigned short* Ws = shm.gemm.Ws;
    int row0 = blockIdx.x * 64;

    for (int i = t; i < 2048; i += 256) {
      int r = i >> 5;
      int c4 = (i & 31) * 4;
      int gr = row0 + r;
      float4 v = (gr < N_NODES) ? *(const float4*)(x + (size_t)gr * D + c4)
                                : float4{0.f, 0.f, 0.f, 0.f};
      unsigned short* p = &As[r * LDA + c4];
      p[0] = f2bf(v.x); p[1] = f2bf(v.y); p[2] = f2bf(v.z); p[3] = f2bf(v.w);
    }
    for (int i = t; i < 4096; i += 256) {
      int r = i >> 5;
      int c4 = (i & 31) * 4;
      float4 wv = *(const float4*)(W + (size_t)r * D + c4);
      unsigned short* q = &Ws[r * LDA + c4];
      q[0] = f2bf(wv.x); q[1] = f2bf(wv.y); q[2] = f2bf(wv.z); q[3] = f2bf(wv.w);
    }
    __syncthreads();

    int w = t >> 6;
    int lane = t & 63;
    int ln = lane & 15;
    int quad = lane >> 4;

    floatx4 acc[8];
#pragma unroll
    for (int n = 0; n < 8; ++n) acc[n] = floatx4{0.f, 0.f, 0.f, 0.f};

#pragma unroll
    for (int ks = 0; ks < 4; ++ks) {
      int kc = ks * 32 + quad * 8;
      bf16x8 a = *(const bf16x8*)&As[(w * 16 + ln) * LDA + kc];
#pragma unroll
      for (int n = 0; n < 8; ++n) {
        bf16x8 bf = *(const bf16x8*)&Ws[(n * 16 + ln) * LDA + kc];
        acc[n] = __builtin_amdgcn_mfma_f32_16x16x32_bf16(a, bf, acc[n], 0, 0, 0);
      }
    }

    // D layout: col = lane&15, row = quad*4 + reg.
    int gr0 = row0 + w * 16 + quad * 4;
#pragma unroll
    for (int n = 0; n < 8; ++n) {
      int gc = n * 16 + ln;
#pragma unroll
      for (int r = 0; r < 4; ++r) {
        int gr = gr0 + r;
        if (gr < N_NODES) y[(size_t)gr * D + gc] = f2bf(acc[n][r]);
      }
    }
  } else {
    // ---------------- bin block: bucket-bin 2048 edges ----------------------
    BinShm& B = shm.bin;
    int blk = blockIdx.x - NB;
    int e0 = blk * BIN_CHUNK;
    for (int i = t; i < NB; i += BIN_T) B.hcnt[i] = 0;
    __syncthreads();

    unsigned pk[8];
    short bk[8];
#pragma unroll
    for (int j = 0; j < 8; ++j) {
      int e = e0 + j * BIN_T + t;
      bk[j] = -1;
      if (e < N_EDGES) {
        int d = dst[e];
        int s = src[e];
        pk[j] = ((unsigned)s << 6) | (unsigned)(d & 63);
        bk[j] = (short)(d >> 6);
        atomicAdd(&B.hcnt[d >> 6], 1);
      }
    }
    __syncthreads();

    // exclusive scan of hcnt[782]: 4 counters/thread (256*4=1024 >= 782)
    int c4[4];
    int s4 = 0;
    int base4 = t * 4;
#pragma unroll
    for (int j = 0; j < 4; ++j) {
      int idx = base4 + j;
      c4[j] = (idx < NB) ? B.hcnt[idx] : 0;
      s4 += c4[j];
    }
    int incl = s4;
    int lane = t & 63, wid = t >> 6;
#pragma unroll
    for (int off = 1; off < 64; off <<= 1) {
      int n = __shfl_up(incl, off);
      if (lane >= off) incl += n;
    }
    if (lane == 63) B.wsums[wid] = incl;
    __syncthreads();
    int wbase = 0;
    for (int w2 = 0; w2 < wid; ++w2) wbase += B.wsums[w2];
    int run = wbase + incl - s4;
#pragma unroll
    for (int j = 0; j < 4; ++j) {
      int idx = base4 + j;
      if (idx < NB) { B.hstart[idx] = run; B.hcur[idx] = run; }
      run += c4[j];
    }
    if (t == BIN_T - 1) B.tot = run;
    __syncthreads();

    // reserve global space: one atomic per nonempty bucket
    for (int i = t; i < NB; i += BIN_T) {
      int c = B.hcnt[i];
      B.hgbase[i] = c ? atomicAdd(&bcursor[i * 16], c) : 0;
    }
    // scatter into stage grouped by bucket (scalar LDS atomics only)
#pragma unroll
    for (int j = 0; j < 8; ++j) {
      if (bk[j] >= 0) {
        int p = atomicAdd(&B.hcur[bk[j]], 1);
        B.stage[p] = pk[j];
        B.stageb[p] = (unsigned short)bk[j];
      }
    }
    __syncthreads();

    // flush: consecutive stage slots of a bucket -> consecutive global addrs
    int tot = B.tot;
    for (int i = t; i < tot; i += BIN_T) {
      int b = B.stageb[i];
      int g = B.hgbase[b] + (i - B.hstart[b]);
      if (g < cap) ebuf[(size_t)b * cap + g] = B.stage[i];
    }
  }
}

// ===========================================================================
// gather_sorted (R9, proven): block per bucket.  In-LDS counting sort by
// local dst (scalar int LDS atomics only), then wave-per-node register
// gather, 4 edges in flight per 16-lane group, shfl reduce, fused bias.
// ===========================================================================
__global__ __launch_bounds__(256) void gather_sorted(
    const unsigned short* __restrict__ y, const unsigned* __restrict__ ebuf,
    const int* __restrict__ bcursor, const float* __restrict__ bias,
    float* __restrict__ out, int cap) {
  __shared__ int cnts[64];
  __shared__ int curs[64];
  __shared__ int starts[65];
  __shared__ int sorted[SORT_CAP];

  int b = blockIdx.x;
  int t = threadIdx.x;
  if (t < 64) cnts[t] = 0;
  __syncthreads();

  int cnt = bcursor[b * 16];
  if (cnt > cap) cnt = cap;
  if (cnt > SORT_CAP) cnt = SORT_CAP;
  const unsigned* eb = ebuf + (size_t)b * cap;

  for (int i = t; i < cnt; i += 256) atomicAdd(&cnts[eb[i] & 63u], 1);
  __syncthreads();

  if (t < 64) {
    int c = cnts[t];
    int v = c;
#pragma unroll
    for (int off = 1; off < 64; off <<= 1) {
      int n = __shfl_up(v, off);
      if (t >= off) v += n;
    }
    starts[t] = v - c;
    curs[t] = v - c;
    if (t == 63) starts[64] = v;
  }
  __syncthreads();

  for (int i = t; i < cnt; i += 256) {
    unsigned u = eb[i];
    int p = atomicAdd(&curs[u & 63u], 1);
    sorted[p] = (int)(u >> 6);
  }
  __syncthreads();

  int wv = t >> 6;
  int lane = t & 63;
  int g = lane >> 4;   // edge subgroup 0..3
  int l = lane & 15;   // 8-col chunk within row
  for (int n = wv; n < 64; n += 4) {
    int node = b * 64 + n;
    int beg = starts[n];
    int end = starts[n + 1];
    float acc[8] = {0.f, 0.f, 0.f, 0.f, 0.f, 0.f, 0.f, 0.f};
    int i = beg + g;
    for (; i + 12 < end; i += 16) {
      int s0 = sorted[i];
      int s1 = sorted[i + 4];
      int s2 = sorted[i + 8];
      int s3 = sorted[i + 12];
      uint4 u0 = *(const uint4*)(y + (size_t)s0 * D + l * 8);
      uint4 u1 = *(const uint4*)(y + (size_t)s1 * D + l * 8);
      uint4 u2 = *(const uint4*)(y + (size_t)s2 * D + l * 8);
      uint4 u3 = *(const uint4*)(y + (size_t)s3 * D + l * 8);
      acc[0] += (bf2f_lo(u0.x) + bf2f_lo(u1.x)) + (bf2f_lo(u2.x) + bf2f_lo(u3.x));
      acc[1] += (bf2f_hi(u0.x) + bf2f_hi(u1.x)) + (bf2f_hi(u2.x) + bf2f_hi(u3.x));
      acc[2] += (bf2f_lo(u0.y) + bf2f_lo(u1.y)) + (bf2f_lo(u2.y) + bf2f_lo(u3.y));
      acc[3] += (bf2f_hi(u0.y) + bf2f_hi(u1.y)) + (bf2f_hi(u2.y) + bf2f_hi(u3.y));
      acc[4] += (bf2f_lo(u0.z) + bf2f_lo(u1.z)) + (bf2f_lo(u2.z) + bf2f_lo(u3.z));
      acc[5] += (bf2f_hi(u0.z) + bf2f_hi(u1.z)) + (bf2f_hi(u2.z) + bf2f_hi(u3.z));
      acc[6] += (bf2f_lo(u0.w) + bf2f_lo(u1.w)) + (bf2f_lo(u2.w) + bf2f_lo(u3.w));
      acc[7] += (bf2f_hi(u0.w) + bf2f_hi(u1.w)) + (bf2f_hi(u2.w) + bf2f_hi(u3.w));
    }
    for (; i < end; i += 4) {
      int s = sorted[i];
      uint4 u = *(const uint4*)(y + (size_t)s * D + l * 8);
      acc[0] += bf2f_lo(u.x); acc[1] += bf2f_hi(u.x);
      acc[2] += bf2f_lo(u.y); acc[3] += bf2f_hi(u.y);
      acc[4] += bf2f_lo(u.z); acc[5] += bf2f_hi(u.z);
      acc[6] += bf2f_lo(u.w); acc[7] += bf2f_hi(u.w);
    }
#pragma unroll
    for (int j = 0; j < 8; ++j) {
      acc[j] += __shfl_xor(acc[j], 16);
      acc[j] += __shfl_xor(acc[j], 32);
    }
    if (g == 0 && node < N_NODES) {
      const float* bp = bias + l * 8;
      float4 r0 = {acc[0] + bp[0], acc[1] + bp[1], acc[2] + bp[2], acc[3] + bp[3]};
      float4 r1 = {acc[4] + bp[4], acc[5] + bp[5], acc[6] + bp[6], acc[7] + bp[7]};
      float* op = out + (size_t)node * D + l * 8;
      *(float4*)op = r0;
      *(float4*)(op + 4) = r1;
    }
  }
}

// ===========================================================================
// Fallback tier 1: CSR path (R5)
// ===========================================================================
__global__ __launch_bounds__(256) void hist_kernel(
    const int* __restrict__ dst, int* __restrict__ counts) {
  int e = blockIdx.x * 256 + threadIdx.x;
  if (e < N_EDGES) atomicAdd(&counts[dst[e]], 1);
}

#define SBLK 196
__global__ __launch_bounds__(256) void reduce_kernel(
    const int* __restrict__ counts, int* __restrict__ blockSums) {
  int i = blockIdx.x * 256 + threadIdx.x;
  int v = (i < N_NODES) ? counts[i] : 0;
#pragma unroll
  for (int off = 32; off; off >>= 1) v += __shfl_down(v, off);
  __shared__ int ws[4];
  int lane = threadIdx.x & 63, wid = threadIdx.x >> 6;
  if (lane == 0) ws[wid] = v;
  __syncthreads();
  if (threadIdx.x == 0) blockSums[blockIdx.x] = ws[0] + ws[1] + ws[2] + ws[3];
}

__global__ __launch_bounds__(256) void scan_kernel2(
    const int* __restrict__ counts, const int* __restrict__ blockSums,
    int* __restrict__ offsets, int* __restrict__ cursor) {
  int b = blockIdx.x;
  int t = threadIdx.x;
  int lane = t & 63, wid = t >> 6;
  int pv = (t < b) ? blockSums[t] : 0;
#pragma unroll
  for (int off = 32; off; off >>= 1) pv += __shfl_down(pv, off);
  __shared__ int ws[4];
  __shared__ int wsum[4];
  __shared__ int base_s;
  if (lane == 0) ws[wid] = pv;
  __syncthreads();
  if (t == 0) base_s = ws[0] + ws[1] + ws[2] + ws[3];
  int i = b * 256 + t;
  int c = (i < N_NODES) ? counts[i] : 0;
  int v = c;
#pragma unroll
  for (int off = 1; off < 64; off <<= 1) {
    int n = __shfl_up(v, off);
    if (lane >= off) v += n;
  }
  if (lane == 63) wsum[wid] = v;
  __syncthreads();
  int wbase = 0;
  for (int w2 = 0; w2 < wid; ++w2) wbase += wsum[w2];
  int excl = base_s + wbase + v - c;
  if (i < N_NODES) {
    offsets[i] = excl;
    cursor[i] = excl;
    if (i == N_NODES - 1) offsets[N_NODES] = excl + c;
  }
}

__global__ __launch_bounds__(256) void fill_kernel(
    const int* __restrict__ src, const int* __restrict__ dst,
    int* __restrict__ cursor, int* __restrict__ esrc) {
  int e = blockIdx.x * 256 + threadIdx.x;
  if (e >= N_EDGES) return;
  int pos = atomicAdd(&cursor[dst[e]], 1);
  esrc[pos] = src[e];
}

__global__ __launch_bounds__(256) void gemm_xw(
    const float* __restrict__ x, const float* __restrict__ W,
    unsigned short* __restrict__ y) {
  __shared__ unsigned short As[64 * LDA];
  __shared__ unsigned short Ws[128 * LDA];
  int t = threadIdx.x;
  int row0 = blockIdx.x * 64;
  for (int i = t; i < 2048; i += 256) {
    int r = i >> 5;
    int c4 = (i & 31) * 4;
    int gr = row0 + r;
    float4 v = (gr < N_NODES) ? *(const float4*)(x + (size_t)gr * D + c4)
                              : float4{0.f, 0.f, 0.f, 0.f};
    unsigned short* p = &As[r * LDA + c4];
    p[0] = f2bf(v.x); p[1] = f2bf(v.y); p[2] = f2bf(v.z); p[3] = f2bf(v.w);
  }
  for (int i = t; i < 4096; i += 256) {
    int r = i >> 5;
    int c4 = (i & 31) * 4;
    float4 wv = *(const float4*)(W + (size_t)r * D + c4);
    unsigned short* q = &Ws[r * LDA + c4];
    q[0] = f2bf(wv.x); q[1] = f2bf(wv.y); q[2] = f2bf(wv.z); q[3] = f2bf(wv.w);
  }
  __syncthreads();
  int w = t >> 6;
  int lane = t & 63;
  int ln = lane & 15;
  int quad = lane >> 4;
  floatx4 acc[8];
#pragma unroll
  for (int n = 0; n < 8; ++n) acc[n] = floatx4{0.f, 0.f, 0.f, 0.f};
#pragma unroll
  for (int ks = 0; ks < 4; ++ks) {
    int kc = ks * 32 + quad * 8;
    bf16x8 a = *(const bf16x8*)&As[(w * 16 + ln) * LDA + kc];
#pragma unroll
    for (int n = 0; n < 8; ++n) {
      bf16x8 bf = *(const bf16x8*)&Ws[(n * 16 + ln) * LDA + kc];
      acc[n] = __builtin_amdgcn_mfma_f32_16x16x32_bf16(a, bf, acc[n], 0, 0, 0);
    }
  }
  int gr0 = row0 + w * 16 + quad * 4;
#pragma unroll
  for (int n = 0; n < 8; ++n) {
    int gc = n * 16 + ln;
#pragma unroll
    for (int r = 0; r < 4; ++r) {
      int gr = gr0 + r;
      if (gr < N_NODES) y[(size_t)gr * D + gc] = f2bf(acc[n][r]);
    }
  }
}

__global__ __launch_bounds__(256) void gather_ybf_kernel(
    const unsigned short* __restrict__ y, const int* __restrict__ esrc,
    const int* __restrict__ offsets, const float* __restrict__ bias,
    float* __restrict__ out) {
  int node = blockIdx.x * 4 + (threadIdx.x >> 6);
  if (node >= N_NODES) return;
  int lane = threadIdx.x & 63;
  int g = lane >> 4;
  int l = lane & 15;
  int beg = offsets[node];
  int end = offsets[node + 1];
  float acc[8] = {0.f, 0.f, 0.f, 0.f, 0.f, 0.f, 0.f, 0.f};
  int i = beg + g;
  for (; i + 4 < end; i += 8) {
    int s0 = esrc[i];
    int s1 = esrc[i + 4];
    uint4 u0 = *(const uint4*)(y + (size_t)s0 * D + l * 8);
    uint4 u1 = *(const uint4*)(y + (size_t)s1 * D + l * 8);
    acc[0] += bf2f_lo(u0.x) + bf2f_lo(u1.x);
    acc[1] += bf2f_hi(u0.x) + bf2f_hi(u1.x);
    acc[2] += bf2f_lo(u0.y) + bf2f_lo(u1.y);
    acc[3] += bf2f_hi(u0.y) + bf2f_hi(u1.y);
    acc[4] += bf2f_lo(u0.z) + bf2f_lo(u1.z);
    acc[5] += bf2f_hi(u0.z) + bf2f_hi(u1.z);
    acc[6] += bf2f_lo(u0.w) + bf2f_lo(u1.w);
    acc[7] += bf2f_hi(u0.w) + bf2f_hi(u1.w);
  }
  if (i < end) {
    int s = esrc[i];
    uint4 u = *(const uint4*)(y + (size_t)s * D + l * 8);
    acc[0] += bf2f_lo(u.x); acc[1] += bf2f_hi(u.x);
    acc[2] += bf2f_lo(u.y); acc[3] += bf2f_hi(u.y);
    acc[4] += bf2f_lo(u.z); acc[5] += bf2f_hi(u.z);
    acc[6] += bf2f_lo(u.w); acc[7] += bf2f_hi(u.w);
  }
#pragma unroll
  for (int j = 0; j < 8; ++j) {
    acc[j] += __shfl_xor(acc[j], 16);
    acc[j] += __shfl_xor(acc[j], 32);
  }
  if (g == 0) {
    const float* bp = bias + l * 8;
    float4 r0 = {acc[0] + bp[0], acc[1] + bp[1], acc[2] + bp[2], acc[3] + bp[3]};
    float4 r1 = {acc[4] + bp[4], acc[5] + bp[5], acc[6] + bp[6], acc[7] + bp[7]};
    float* op = out + (size_t)node * D + l * 8;
    *(float4*)op = r0;
    *(float4*)(op + 4) = r1;
  }
}

// ===========================================================================
// Fallback tier 2: atomic scatter + f32 transform.
// ===========================================================================
__global__ __launch_bounds__(256) void scatter_kernel(
    const float* __restrict__ x, const int* __restrict__ src,
    const int* __restrict__ dst, float* __restrict__ out) {
  int gtid = blockIdx.x * 256 + threadIdx.x;
  int e = gtid >> 6;
  int lane = threadIdx.x & 63;
  if (e >= N_EDGES) return;
  float2 v = ((const float2*)(x + (size_t)src[e] * D))[lane];
  float* orow = out + (size_t)dst[e] * D + lane * 2;
  atomicAdd(orow + 0, v.x);
  atomicAdd(orow + 1, v.y);
}

__global__ __launch_bounds__(256) void transform_kernel(
    float* __restrict__ out, const float* __restrict__ W,
    const float* __restrict__ bias) {
  constexpr int RPB = 64;
  constexpr int HP = 132;
  __shared__ float Hs[RPB][HP];
  int t = threadIdx.x;
  int row0 = blockIdx.x * RPB;
  int nr = min(RPB, N_NODES - row0);
  {
    const float4* g = (const float4*)(out + (size_t)row0 * D);
    for (int i = t; i < nr * (D / 4); i += 256) {
      int r = i >> 5;
      int c = (i & 31) * 4;
      *(float4*)&Hs[r][c] = g[i];
    }
  }
  __syncthreads();
  int tx = t & 15;
  int ty = t >> 4;
  int r0 = ty * 4;
  for (int half = 0; half < 2; ++half) {
    int oc0 = half * 64 + tx * 4;
    const float* Wb = W + (size_t)oc0 * D;
    float4 a0 = {0.f, 0.f, 0.f, 0.f}, a1 = {0.f, 0.f, 0.f, 0.f};
    float4 a2 = {0.f, 0.f, 0.f, 0.f}, a3 = {0.f, 0.f, 0.f, 0.f};
#pragma unroll 8
    for (int k = 0; k < D; k += 4) {
      float4 w0 = *(const float4*)(Wb + 0 * D + k);
      float4 w1 = *(const float4*)(Wb + 1 * D + k);
      float4 w2 = *(const float4*)(Wb + 2 * D + k);
      float4 w3 = *(const float4*)(Wb + 3 * D + k);
      float4 h0 = *(const float4*)&Hs[r0 + 0][k];
      float4 h1 = *(const float4*)&Hs[r0 + 1][k];
      float4 h2 = *(const float4*)&Hs[r0 + 2][k];
      float4 h3 = *(const float4*)&Hs[r0 + 3][k];
#define DOT(hv, wv) fmaf((hv).w, (wv).w, fmaf((hv).z, (wv).z, fmaf((hv).y, (wv).y, (hv).x * (wv).x)))
      a0.x += DOT(h0, w0); a0.y += DOT(h0, w1); a0.z += DOT(h0, w2); a0.w += DOT(h0, w3);
      a1.x += DOT(h1, w0); a1.y += DOT(h1, w1); a1.z += DOT(h1, w2); a1.w += DOT(h1, w3);
      a2.x += DOT(h2, w0); a2.y += DOT(h2, w1); a2.z += DOT(h2, w2); a2.w += DOT(h2, w3);
      a3.x += DOT(h3, w0); a3.y += DOT(h3, w1); a3.z += DOT(h3, w2); a3.w += DOT(h3, w3);
#undef DOT
    }
    float4 bv = *(const float4*)(bias + oc0);
    a0.x += bv.x; a0.y += bv.y; a0.z += bv.z; a0.w += bv.w;
    a1.x += bv.x; a1.y += bv.y; a1.z += bv.z; a1.w += bv.w;
    a2.x += bv.x; a2.y += bv.y; a2.z += bv.z; a2.w += bv.w;
    a3.x += bv.x; a3.y += bv.y; a3.z += bv.z; a3.w += bv.w;
    if (r0 + 0 < nr) *(float4*)(out + (size_t)(row0 + r0 + 0) * D + oc0) = a0;
    if (r0 + 1 < nr) *(float4*)(out + (size_t)(row0 + r0 + 1) * D + oc0) = a1;
    if (r0 + 2 < nr) *(float4*)(out + (size_t)(row0 + r0 + 2) * D + oc0) = a2;
    if (r0 + 3 < nr) *(float4*)(out + (size_t)(row0 + r0 + 3) * D + oc0) = a3;
  }
}

extern "C" void kernel_launch(void* const* d_in, const int* in_sizes, int n_in,
                              void* d_out, int out_size, void* d_ws, size_t ws_size,
                              hipStream_t stream) {
  const float* x = (const float*)d_in[0];
  const int* src = (const int*)d_in[1];
  const int* dst = (const int*)d_in[2];
  const float* W = (const float*)d_in[3];
  const float* b = (const float*)d_in[4];
  float* out = (float*)d_out;

  const size_t ybytes = (size_t)N_NODES * D * sizeof(unsigned short);  // 12.8 MB
  const size_t bcbytes = (size_t)NB * 16 * sizeof(int);                // 50 KB

  long long avail = (long long)ws_size - (long long)ybytes - (long long)bcbytes;
  int cap = 0;
  if (avail > 0) {
    long long c = avail / (4LL * NB);
    cap = (c > SORT_CAP) ? SORT_CAP : (int)c;
  }

  if (cap >= 1344) {  // bucket sizes ~Poisson(1024): mean + 10 sigma
    unsigned short* y = (unsigned short*)d_ws;
    int* bcursor = (int*)((char*)d_ws + ybytes);
    unsigned* ebuf = (unsigned*)((char*)bcursor + bcbytes);

    hipMemsetAsync(bcursor, 0, bcbytes, stream);
    prep_kernel<<<NB + BIN_BLOCKS, 256, 0, stream>>>(x, W, y, src, dst,
                                                     bcursor, ebuf, cap);
    gather_sorted<<<NB, 256, 0, stream>>>(y, ebuf, bcursor, b, out, cap);
    return;
  }

  const size_t A = 50048;
  const size_t head_ints = 3 * A + 256 + (size_t)N_EDGES;
  const size_t need_csr = head_ints * sizeof(int) + ybytes;

  if (ws_size >= need_csr) {
    int* counts     = (int*)d_ws;
    int* offsets    = counts + A;
    int* cursor     = offsets + A;
    int* blockSums  = cursor + A;
    int* esrc       = blockSums + 256;
    unsigned short* y = (unsigned short*)(esrc + N_EDGES);

    hipMemsetAsync(counts, 0, N_NODES * sizeof(int), stream);
    hist_kernel<<<(N_EDGES + 255) / 256, 256, 0, stream>>>(dst, counts);
    reduce_kernel<<<SBLK, 256, 0, stream>>>(counts, blockSums);
    scan_kernel2<<<SBLK, 256, 0, stream>>>(counts, blockSums, offsets, cursor);
    fill_kernel<<<(N_EDGES + 255) / 256, 256, 0, stream>>>(src, dst, cursor, esrc);
    gemm_xw<<<NB, 256, 0, stream>>>(x, W, y);
    gather_ybf_kernel<<<(N_NODES + 3) / 4, 256, 0, stream>>>(y, esrc, offsets, b, out);
  } else {
    hipMemsetAsync(out, 0, (size_t)N_NODES * D * sizeof(float), stream);
    scatter_kernel<<<N_EDGES / 4, 256, 0, stream>>>(x, src, dst, out);
    transform_kernel<<<(N_NODES + 63) / 64, 256, 0, stream>>>(out, W, b);
  }
}